// Round 1
// baseline (739.708 us; speedup 1.0000x reference)
//
#include <hip/hip_runtime.h>
#include <math.h>

// TopKMoEGate: logits = x @ W^T ; noisy = logits + noise * nw ; top-2 ;
// sparse softmax scatter. Outputs (float32, concatenated):
//   gated_probs [M,64] | top_idx [M,2] (as float) | top_vals [M,2]
//
// Block = 64 tokens x 64 experts, BK=64, 4x4 register tile per thread.
// LDS tiles transposed [k][m] with stride 68 (16B-aligned rows, <=2-way
// bank conflicts on ds_read_b128).

constexpr int EXP = 64;   // experts
constexpr int BM  = 64;   // tokens per block
constexpr int BK  = 64;   // k-tile
constexpr int LDT = 68;   // padded [k][*] stride (multiple of 4 for b128 align)

__device__ double dot_fp64(const float* __restrict__ a,
                           const float* __restrict__ b, int D) {
    double s = 0.0;
    for (int d = 0; d < D; ++d) s += (double)a[d] * (double)b[d];
    return s;
}

__global__ __launch_bounds__(256)
void moe_gate_kernel(const float* __restrict__ x,      // [M, D]
                     const float* __restrict__ W,      // [EXP, D]
                     const float* __restrict__ nw,     // [EXP]
                     const float* __restrict__ noise,  // [M, EXP]
                     float* __restrict__ probs,        // [M, EXP]
                     float* __restrict__ idx_out,      // [M, 2] (float-encoded)
                     float* __restrict__ val_out,      // [M, 2]
                     int D)
{
    __shared__ float xs[BK][LDT];        // [k][token]
    __shared__ float ws[BK][LDT];        // [k][expert]
    __shared__ float ls[BM][EXP + 1];    // logits [token][expert], +1 pad
    __shared__ float s_p0[BM], s_p1[BM];
    __shared__ int   s_i0[BM], s_i1[BM];

    const int tid = threadIdx.x;
    const int tx  = tid & 15;        // expert group
    const int ty  = tid >> 4;        // token group
    const int m0  = blockIdx.x * BM;

    float acc[4][4] = {{0.f, 0.f, 0.f, 0.f},
                       {0.f, 0.f, 0.f, 0.f},
                       {0.f, 0.f, 0.f, 0.f},
                       {0.f, 0.f, 0.f, 0.f}};

    for (int kt = 0; kt < D; kt += BK) {
        // ---- stage tiles (transpose into [k][m]) ----
        const int col = tx * 4;  // k offset within tile
#pragma unroll
        for (int r = 0; r < 4; ++r) {
            const int row = ty + r * 16;  // token / expert row
            const float4 vx =
                *(const float4*)(x + (size_t)(m0 + row) * D + kt + col);
            xs[col + 0][row] = vx.x;
            xs[col + 1][row] = vx.y;
            xs[col + 2][row] = vx.z;
            xs[col + 3][row] = vx.w;
            const float4 vw =
                *(const float4*)(W + (size_t)row * D + kt + col);
            ws[col + 0][row] = vw.x;
            ws[col + 1][row] = vw.y;
            ws[col + 2][row] = vw.z;
            ws[col + 3][row] = vw.w;
        }
        __syncthreads();

        // ---- compute ----
#pragma unroll 8
        for (int k = 0; k < BK; ++k) {
            const float4 a4 = *(const float4*)(&xs[k][ty * 4]);
            const float4 b4 = *(const float4*)(&ws[k][tx * 4]);
            const float av[4] = {a4.x, a4.y, a4.z, a4.w};
            const float bv[4] = {b4.x, b4.y, b4.z, b4.w};
#pragma unroll
            for (int i = 0; i < 4; ++i)
#pragma unroll
                for (int j = 0; j < 4; ++j)
                    acc[i][j] = fmaf(av[i], bv[j], acc[i][j]);
        }
        __syncthreads();
    }

    // ---- logits -> LDS ----
#pragma unroll
    for (int i = 0; i < 4; ++i)
#pragma unroll
        for (int j = 0; j < 4; ++j)
            ls[ty * 4 + i][tx * 4 + j] = acc[i][j];
    __syncthreads();

    // ---- add noise * noise_weight (coalesced) ----
#pragma unroll
    for (int r = 0; r < 16; ++r) {
        const int pos = r * 256 + tid;         // 0..4095
        const int t = pos >> 6, e = pos & 63;
        ls[t][e] = fmaf(noise[(size_t)m0 * EXP + pos], nw[e], ls[t][e]);
    }
    __syncthreads();

    // ---- per-token top-2 (one thread per token) ----
    if (tid < BM) {
        const int t = tid;
        const int g = m0 + t;
        float v0 = -INFINITY, v1 = -INFINITY, v2 = -INFINITY;
        int   i0 = 0, i1 = 0, i2 = 0;
        for (int e = 0; e < EXP; ++e) {
            const float v = ls[t][e];
            if (v > v0)      { v2 = v1; i2 = i1; v1 = v0; i1 = i0; v0 = v; i0 = e; }
            else if (v > v1) { v2 = v1; i2 = i1; v1 = v;  i1 = e; }
            else if (v > v2) { v2 = v;  i2 = e; }
        }

        // near-tie guard: fp64 recompute + re-rank of top-3 candidates
        const float eps = 1e-3f;
        if ((v0 - v1) < eps || (v1 - v2) < eps) {
            double d0 = dot_fp64(x + (size_t)g * D, W + (size_t)i0 * D, D)
                      + (double)noise[(size_t)g * EXP + i0] * (double)nw[i0];
            double d1 = dot_fp64(x + (size_t)g * D, W + (size_t)i1 * D, D)
                      + (double)noise[(size_t)g * EXP + i1] * (double)nw[i1];
            double d2 = dot_fp64(x + (size_t)g * D, W + (size_t)i2 * D, D)
                      + (double)noise[(size_t)g * EXP + i2] * (double)nw[i2];
            // sort 3 pairs: value desc, index asc on ties
            #define CSWAP(va, ia, vb, ib)                                   \
                if ((vb > va) || (vb == va && ib < ia)) {                   \
                    double tv = va; va = vb; vb = tv;                       \
                    int ti = ia; ia = ib; ib = ti; }
            CSWAP(d0, i0, d1, i1)
            CSWAP(d1, i1, d2, i2)
            CSWAP(d0, i0, d1, i1)
            #undef CSWAP
            v0 = (float)d0; v1 = (float)d1;
        }

        const float e1 = expf(v1 - v0);
        const float inv = 1.0f / (1.0f + e1);
        const float p0 = inv;
        const float p1 = e1 * inv;
        s_i0[t] = i0; s_i1[t] = i1;
        s_p0[t] = p0; s_p1[t] = p1;

        idx_out[(size_t)g * 2 + 0] = (float)i0;
        idx_out[(size_t)g * 2 + 1] = (float)i1;
        val_out[(size_t)g * 2 + 0] = v0;
        val_out[(size_t)g * 2 + 1] = v1;
    }
    __syncthreads();

    // ---- sparse softmax scatter (coalesced) ----
#pragma unroll
    for (int r = 0; r < 16; ++r) {
        const int pos = r * 256 + tid;
        const int t = pos >> 6, e = pos & 63;
        float p = 0.0f;
        if (e == s_i0[t]) p = s_p0[t];
        else if (e == s_i1[t]) p = s_p1[t];
        probs[(size_t)m0 * EXP + pos] = p;
    }
}

extern "C" void kernel_launch(void* const* d_in, const int* in_sizes, int n_in,
                              void* d_out, int out_size, void* d_ws, size_t ws_size,
                              hipStream_t stream) {
    const float* x     = (const float*)d_in[0];  // [B,S,D]
    const float* W     = (const float*)d_in[1];  // [E,D]
    const float* nw    = (const float*)d_in[2];  // [E]
    const float* noise = (const float*)d_in[3];  // [B,S,E]

    const int M = in_sizes[3] / EXP;             // B*S tokens
    const int D = in_sizes[0] / M;               // feature dim

    float* probs   = (float*)d_out;              // [M, E]
    float* idx_out = probs + (size_t)M * EXP;    // [M, 2]
    float* val_out = idx_out + (size_t)M * 2;    // [M, 2]

    const int grid = M / BM;                     // 256 blocks
    moe_gate_kernel<<<grid, 256, 0, stream>>>(x, W, nw, noise,
                                              probs, idx_out, val_out, D);
}

// Round 2
// 640.776 us; speedup vs baseline: 1.1544x; 1.1544x over previous
//
#include <hip/hip_runtime.h>
#include <math.h>

// TopKMoEGate: logits = x @ W^T ; noisy = logits + noise*nw ; top-2 ;
// sparse softmax scatter. Outputs (float32, concatenated):
//   gated_probs [M,64] | top_idx [M,2] (as float) | top_vals [M,2]
//
// Layout: lane = expert (E=64 = wave width). Each wave owns 8 tokens.
//   - x operand: wave-uniform rows -> s_load into SGPRs (free on VALU/LDS)
//   - W operand: staged transposed in LDS (stride 65 -> 2-way conflicts = free)
//   - top-2 via shuffle butterflies; fp64 tie-guard is wave-parallel.

constexpr int EXPN = 64;   // experts == wave width
constexpr int TPW  = 8;    // tokens per wave
constexpr int WPB  = 4;    // waves per block
constexpr int TPB  = TPW * WPB;  // 32 tokens per block
constexpr int BK   = 64;   // k-chunk staged per barrier

__global__ __launch_bounds__(256)
void moe_gate_kernel(const float* __restrict__ x,      // [M, D]
                     const float* __restrict__ W,      // [E, D]
                     const float* __restrict__ nw,     // [E]
                     const float* __restrict__ noise,  // [M, E]
                     float* __restrict__ probs,        // [M, E]
                     float* __restrict__ idx_out,      // [M, 2] float-encoded
                     float* __restrict__ val_out,      // [M, 2]
                     int D)
{
    __shared__ float wt[BK][EXPN + 1];   // W^T tile [k][expert], +1 pad

    const int tid  = threadIdx.x;
    const int lane = tid & 63;                                // expert id
    const int wv   = __builtin_amdgcn_readfirstlane(tid) >> 6; // wave id (SGPR)
    const int m0   = blockIdx.x * TPB + wv * TPW;              // uniform token base

    float acc[TPW];
#pragma unroll
    for (int t = 0; t < TPW; ++t) acc[t] = 0.f;

    for (int kc = 0; kc < D; kc += BK) {
        // ---- stage W[0..63][kc..kc+63] transposed into LDS ----
        {
            const int r = tid >> 2;   // expert row 0..63
            const int c = tid & 3;    // k sub-chunk
#pragma unroll
            for (int j = 0; j < 4; ++j) {
                const int ko = j * 16 + c * 4;
                const float4 v = *(const float4*)(W + (size_t)r * D + kc + ko);
                wt[ko + 0][r] = v.x;
                wt[ko + 1][r] = v.y;
                wt[ko + 2][r] = v.z;
                wt[ko + 3][r] = v.w;
            }
        }
        __syncthreads();

        // ---- compute: 8 tokens x 4 k per iter ----
#pragma unroll 4
        for (int k4 = 0; k4 < BK; k4 += 4) {
            const float w0 = wt[k4 + 0][lane];
            const float w1 = wt[k4 + 1][lane];
            const float w2 = wt[k4 + 2][lane];
            const float w3 = wt[k4 + 3][lane];
#pragma unroll
            for (int t = 0; t < TPW; ++t) {
                // uniform address -> s_load_dwordx4
                const float4 xv =
                    *(const float4*)(x + (size_t)(m0 + t) * D + kc + k4);
                acc[t] = fmaf(xv.x, w0, acc[t]);
                acc[t] = fmaf(xv.y, w1, acc[t]);
                acc[t] = fmaf(xv.z, w2, acc[t]);
                acc[t] = fmaf(xv.w, w3, acc[t]);
            }
        }
        __syncthreads();
    }

    // ---- epilogue: per-token noisy top-2 + sparse softmax ----
    const float nwv = nw[lane];

#pragma unroll 1
    for (int t = 0; t < TPW; ++t) {
        const int g = m0 + t;
        const float logit = fmaf(noise[(size_t)g * EXPN + lane], nwv, acc[t]);

        // top-1 (prefer lower index on exact tie, like torch/jax top_k)
        float v0; int i0;
        {
            float v = logit; int ix = lane;
#pragma unroll
            for (int off = 32; off; off >>= 1) {
                const float vo = __shfl_xor(v, off);
                const int   io = __shfl_xor(ix, off);
                if (vo > v || (vo == v && io < ix)) { v = vo; ix = io; }
            }
            v0 = v; i0 = ix;
        }
        // top-2
        float v1; int i1;
        {
            float v = (lane == i0) ? -INFINITY : logit; int ix = lane;
#pragma unroll
            for (int off = 32; off; off >>= 1) {
                const float vo = __shfl_xor(v, off);
                const int   io = __shfl_xor(ix, off);
                if (vo > v || (vo == v && io < ix)) { v = vo; ix = io; }
            }
            v1 = v; i1 = ix;
        }
        // top-3 value only (for the tie guard)
        float v2;
        {
            float v = (lane == i0 || lane == i1) ? -INFINITY : logit; int ix = lane;
#pragma unroll
            for (int off = 32; off; off >>= 1) {
                const float vo = __shfl_xor(v, off);
                const int   io = __shfl_xor(ix, off);
                if (vo > v || (vo == v && io < ix)) { v = vo; ix = io; }
            }
            v2 = v;
        }

        // near-tie guard: fp64 recompute of ALL 64 logits, wave-parallel
        const float eps = 1e-3f;
        if ((v0 - v1) < eps || (v1 - v2) < eps) {
            const float* xr = x + (size_t)g * D;      // uniform -> s_load
            const float* wr = W + (size_t)lane * D;   // per-lane row
            double d0 = 0.0, d1 = 0.0, d2 = 0.0, d3 = 0.0;
            for (int d = 0; d < D; d += 4) {
                d0 += (double)xr[d + 0] * (double)wr[d + 0];
                d1 += (double)xr[d + 1] * (double)wr[d + 1];
                d2 += (double)xr[d + 2] * (double)wr[d + 2];
                d3 += (double)xr[d + 3] * (double)wr[d + 3];
            }
            double dl = (d0 + d1) + (d2 + d3)
                      + (double)noise[(size_t)g * EXPN + lane] * (double)nwv;

            double dv0; int di0;
            {
                double v = dl; int ix = lane;
#pragma unroll
                for (int off = 32; off; off >>= 1) {
                    const double vo = __shfl_xor(v, off);
                    const int    io = __shfl_xor(ix, off);
                    if (vo > v || (vo == v && io < ix)) { v = vo; ix = io; }
                }
                dv0 = v; di0 = ix;
            }
            double dv1; int di1;
            {
                double v = (lane == di0) ? -INFINITY : dl; int ix = lane;
#pragma unroll
                for (int off = 32; off; off >>= 1) {
                    const double vo = __shfl_xor(v, off);
                    const int    io = __shfl_xor(ix, off);
                    if (vo > v || (vo == v && io < ix)) { v = vo; ix = io; }
                }
                dv1 = v; di1 = ix;
            }
            v0 = (float)dv0; i0 = di0;
            v1 = (float)dv1; i1 = di1;
        }

        const float e1  = expf(v1 - v0);
        const float inv = 1.0f / (1.0f + e1);

        float p = 0.f;
        if (lane == i0)      p = inv;
        else if (lane == i1) p = e1 * inv;
        probs[(size_t)g * EXPN + lane] = p;

        if (lane == 0) {
            idx_out[(size_t)g * 2 + 0] = (float)i0;
            idx_out[(size_t)g * 2 + 1] = (float)i1;
            val_out[(size_t)g * 2 + 0] = v0;
            val_out[(size_t)g * 2 + 1] = v1;
        }
    }
}

extern "C" void kernel_launch(void* const* d_in, const int* in_sizes, int n_in,
                              void* d_out, int out_size, void* d_ws, size_t ws_size,
                              hipStream_t stream) {
    const float* x     = (const float*)d_in[0];  // [B,S,D]
    const float* W     = (const float*)d_in[1];  // [E,D]
    const float* nw    = (const float*)d_in[2];  // [E]
    const float* noise = (const float*)d_in[3];  // [B,S,E]

    const int M = in_sizes[3] / EXPN;            // B*S tokens (16384)
    const int D = in_sizes[0] / M;               // feature dim (2048)

    float* probs   = (float*)d_out;              // [M, E]
    float* idx_out = probs + (size_t)M * EXPN;   // [M, 2]
    float* val_out = idx_out + (size_t)M * 2;    // [M, 2]

    const int grid = M / TPB;                    // 512 blocks
    moe_gate_kernel<<<grid, 256, 0, stream>>>(x, W, nw, noise,
                                              probs, idx_out, val_out, D);
}

// Round 3
// 356.013 us; speedup vs baseline: 2.0778x; 1.7999x over previous
//
#include <hip/hip_runtime.h>
#include <math.h>

// TopKMoEGate via split-bf16 MFMA:
//   x = xh + xl, W = wh + wl (bf16 hi/lo); logits = xh*wh + xh*wl + xl*wh
//   (fp32-accurate to ~1e-5; fp64 tie-guard protects top-k index exactness).
// Block: 32 tokens x 64 experts, BK=64, double-buffered LDS, 1 barrier/iter.
// Wave w: token-half (w&1), expert-half (w>>1); 16x16x32 bf16 MFMA.

typedef __attribute__((ext_vector_type(8))) __bf16 bf16x8;
typedef __attribute__((ext_vector_type(8))) unsigned short u16x8;
typedef __attribute__((ext_vector_type(4))) float f32x4;

constexpr int EXPN = 64;   // experts
constexpr int BM   = 32;   // tokens per block
constexpr int BK   = 64;   // k chunk
constexpr int LDK  = BK + 8;  // 72 bf16 = 144 B row stride (16B-aligned, conflict-free)

__device__ __forceinline__ void split2(float f, unsigned short& h, unsigned short& l) {
    const unsigned b = __float_as_uint(f);
    h = (unsigned short)(b >> 16);                       // bf16 hi (truncate)
    const float fh = __uint_as_float(b & 0xffff0000u);
    l = (unsigned short)(__float_as_uint(f - fh) >> 16); // bf16 lo
}

__global__ __launch_bounds__(256)
void moe_gate_kernel(const float* __restrict__ x,      // [M, D]
                     const float* __restrict__ W,      // [E, D]
                     const float* __restrict__ nw,     // [E]
                     const float* __restrict__ noise,  // [M, E]
                     float* __restrict__ probs,        // [M, E]
                     float* __restrict__ idx_out,      // [M, 2] float-encoded
                     float* __restrict__ val_out,      // [M, 2]
                     int D)
{
    __shared__ unsigned short xh[2][BM][LDK], xl[2][BM][LDK];     // 18.4 KB
    __shared__ unsigned short wh[2][EXPN][LDK], wl[2][EXPN][LDK]; // 36.9 KB
    __shared__ float ls[BM][EXPN + 1];                            // 8.3 KB

    const int tid  = threadIdx.x;
    const int lane = tid & 63;
    const int wv   = tid >> 6;
    const int hh   = wv & 1;        // token half (16 tokens)
    const int qq   = wv >> 1;       // expert half (32 experts)
    const int m0   = blockIdx.x * BM;

    // staging assignment
    const int xrow = tid >> 3;          // 0..31 token
    const int xcol = (tid & 7) * 8;     // k offset (8 floats / thread)
    const int wrow = tid >> 2;          // 0..63 expert
    const int wcol = (tid & 3) * 16;    // k offset (16 floats / thread)

    const float* xbase = x + (size_t)(m0 + xrow) * D + xcol;
    const float* wbase = W + (size_t)wrow * D + wcol;

    f32x4 acc0 = {0.f, 0.f, 0.f, 0.f};
    f32x4 acc1 = {0.f, 0.f, 0.f, 0.f};

    float4 xr0, xr1, wr0, wr1, wr2, wr3;
    xr0 = *(const float4*)(xbase);
    xr1 = *(const float4*)(xbase + 4);
    wr0 = *(const float4*)(wbase);
    wr1 = *(const float4*)(wbase + 4);
    wr2 = *(const float4*)(wbase + 8);
    wr3 = *(const float4*)(wbase + 12);

    const int nchunk = D / BK;          // 32
    const int fr = lane & 15;           // m (tokens) / n (experts) in frag
    const int kq = (lane >> 4) * 8;     // k sub-offset in frag

    for (int c = 0; c < nchunk; ++c) {
        const int buf = c & 1;

        // ---- convert + stage into LDS ----
        {
            const float xv[8] = {xr0.x, xr0.y, xr0.z, xr0.w,
                                 xr1.x, xr1.y, xr1.z, xr1.w};
            u16x8 hv, lv;
#pragma unroll
            for (int i = 0; i < 8; ++i) {
                unsigned short a, b; split2(xv[i], a, b);
                hv[i] = a; lv[i] = b;
            }
            *(u16x8*)&xh[buf][xrow][xcol] = hv;
            *(u16x8*)&xl[buf][xrow][xcol] = lv;

            const float wvv[16] = {wr0.x, wr0.y, wr0.z, wr0.w,
                                   wr1.x, wr1.y, wr1.z, wr1.w,
                                   wr2.x, wr2.y, wr2.z, wr2.w,
                                   wr3.x, wr3.y, wr3.z, wr3.w};
            u16x8 h0, l0, h1, l1;
#pragma unroll
            for (int i = 0; i < 8; ++i) {
                unsigned short a, b; split2(wvv[i], a, b);
                h0[i] = a; l0[i] = b;
                split2(wvv[i + 8], a, b);
                h1[i] = a; l1[i] = b;
            }
            *(u16x8*)&wh[buf][wrow][wcol]     = h0;
            *(u16x8*)&wl[buf][wrow][wcol]     = l0;
            *(u16x8*)&wh[buf][wrow][wcol + 8] = h1;
            *(u16x8*)&wl[buf][wrow][wcol + 8] = l1;
        }
        __syncthreads();

        // ---- prefetch next chunk (lands during MFMA phase) ----
        if (c + 1 < nchunk) {
            const float* xp = xbase + (c + 1) * BK;
            xr0 = *(const float4*)(xp);
            xr1 = *(const float4*)(xp + 4);
            const float* wp = wbase + (c + 1) * BK;
            wr0 = *(const float4*)(wp);
            wr1 = *(const float4*)(wp + 4);
            wr2 = *(const float4*)(wp + 8);
            wr3 = *(const float4*)(wp + 12);
        }

        // ---- MFMA on current chunk ----
#pragma unroll
        for (int ks = 0; ks < BK; ks += 32) {
            const bf16x8 ah  = *(const bf16x8*)&xh[buf][hh * 16 + fr][ks + kq];
            const bf16x8 al  = *(const bf16x8*)&xl[buf][hh * 16 + fr][ks + kq];
            const bf16x8 b0h = *(const bf16x8*)&wh[buf][qq * 32 + fr][ks + kq];
            const bf16x8 b0l = *(const bf16x8*)&wl[buf][qq * 32 + fr][ks + kq];
            const bf16x8 b1h = *(const bf16x8*)&wh[buf][qq * 32 + 16 + fr][ks + kq];
            const bf16x8 b1l = *(const bf16x8*)&wl[buf][qq * 32 + 16 + fr][ks + kq];
            acc0 = __builtin_amdgcn_mfma_f32_16x16x32_bf16(ah, b0h, acc0, 0, 0, 0);
            acc0 = __builtin_amdgcn_mfma_f32_16x16x32_bf16(ah, b0l, acc0, 0, 0, 0);
            acc0 = __builtin_amdgcn_mfma_f32_16x16x32_bf16(al, b0h, acc0, 0, 0, 0);
            acc1 = __builtin_amdgcn_mfma_f32_16x16x32_bf16(ah, b1h, acc1, 0, 0, 0);
            acc1 = __builtin_amdgcn_mfma_f32_16x16x32_bf16(ah, b1l, acc1, 0, 0, 0);
            acc1 = __builtin_amdgcn_mfma_f32_16x16x32_bf16(al, b1h, acc1, 0, 0, 0);
        }
    }

    // ---- C/D layout: col = lane&15, row = (lane>>4)*4 + reg ----
    const int trow = hh * 16 + (lane >> 4) * 4;
#pragma unroll
    for (int r = 0; r < 4; ++r) {
        ls[trow + r][qq * 32 + fr]      = acc0[r];
        ls[trow + r][qq * 32 + 16 + fr] = acc1[r];
    }
    __syncthreads();

    // ---- epilogue: per-token noisy top-2 + sparse softmax (lane = expert) ----
    const float nwv = nw[lane];

#pragma unroll 1
    for (int t = 0; t < 8; ++t) {
        const int tl = wv * 8 + t;       // local token
        const int g  = m0 + tl;          // global token
        const float logit = fmaf(noise[(size_t)g * EXPN + lane], nwv, ls[tl][lane]);

        float v0; int i0;
        {
            float v = logit; int ix = lane;
#pragma unroll
            for (int off = 32; off; off >>= 1) {
                const float vo = __shfl_xor(v, off);
                const int   io = __shfl_xor(ix, off);
                if (vo > v || (vo == v && io < ix)) { v = vo; ix = io; }
            }
            v0 = v; i0 = ix;
        }
        float v1; int i1;
        {
            float v = (lane == i0) ? -INFINITY : logit; int ix = lane;
#pragma unroll
            for (int off = 32; off; off >>= 1) {
                const float vo = __shfl_xor(v, off);
                const int   io = __shfl_xor(ix, off);
                if (vo > v || (vo == v && io < ix)) { v = vo; ix = io; }
            }
            v1 = v; i1 = ix;
        }
        float v2;
        {
            float v = (lane == i0 || lane == i1) ? -INFINITY : logit; int ix = lane;
#pragma unroll
            for (int off = 32; off; off >>= 1) {
                const float vo = __shfl_xor(v, off);
                const int   io = __shfl_xor(ix, off);
                if (vo > v || (vo == v && io < ix)) { v = vo; ix = io; }
            }
            v2 = v;
        }

        // near-tie guard: fp64 recompute of all 64 logits, wave-parallel
        const float eps = 1e-3f;
        if ((v0 - v1) < eps || (v1 - v2) < eps) {
            const float* xr = x + (size_t)g * D;
            const float* wr = W + (size_t)lane * D;
            double d0 = 0.0, d1 = 0.0, d2 = 0.0, d3 = 0.0;
            for (int d = 0; d < D; d += 4) {
                d0 += (double)xr[d + 0] * (double)wr[d + 0];
                d1 += (double)xr[d + 1] * (double)wr[d + 1];
                d2 += (double)xr[d + 2] * (double)wr[d + 2];
                d3 += (double)xr[d + 3] * (double)wr[d + 3];
            }
            double dl = (d0 + d1) + (d2 + d3)
                      + (double)noise[(size_t)g * EXPN + lane] * (double)nwv;

            double dv0; int di0;
            {
                double v = dl; int ix = lane;
#pragma unroll
                for (int off = 32; off; off >>= 1) {
                    const double vo = __shfl_xor(v, off);
                    const int    io = __shfl_xor(ix, off);
                    if (vo > v || (vo == v && io < ix)) { v = vo; ix = io; }
                }
                dv0 = v; di0 = ix;
            }
            double dv1; int di1;
            {
                double v = (lane == di0) ? -INFINITY : dl; int ix = lane;
#pragma unroll
                for (int off = 32; off; off >>= 1) {
                    const double vo = __shfl_xor(v, off);
                    const int    io = __shfl_xor(ix, off);
                    if (vo > v || (vo == v && io < ix)) { v = vo; ix = io; }
                }
                dv1 = v; di1 = ix;
            }
            v0 = (float)dv0; i0 = di0;
            v1 = (float)dv1; i1 = di1;
        }

        const float e1  = expf(v1 - v0);
        const float inv = 1.0f / (1.0f + e1);

        float p = 0.f;
        if (lane == i0)      p = inv;
        else if (lane == i1) p = e1 * inv;
        probs[(size_t)g * EXPN + lane] = p;

        if (lane == 0) {
            idx_out[(size_t)g * 2 + 0] = (float)i0;
            idx_out[(size_t)g * 2 + 1] = (float)i1;
            val_out[(size_t)g * 2 + 0] = v0;
            val_out[(size_t)g * 2 + 1] = v1;
        }
    }
}

extern "C" void kernel_launch(void* const* d_in, const int* in_sizes, int n_in,
                              void* d_out, int out_size, void* d_ws, size_t ws_size,
                              hipStream_t stream) {
    const float* x     = (const float*)d_in[0];  // [B,S,D]
    const float* W     = (const float*)d_in[1];  // [E,D]
    const float* nw    = (const float*)d_in[2];  // [E]
    const float* noise = (const float*)d_in[3];  // [B,S,E]

    const int M = in_sizes[3] / EXPN;            // 16384 tokens
    const int D = in_sizes[0] / M;               // 2048

    float* probs   = (float*)d_out;              // [M, E]
    float* idx_out = probs + (size_t)M * EXPN;   // [M, 2]
    float* val_out = idx_out + (size_t)M * 2;    // [M, 2]

    const int grid = M / BM;                     // 512 blocks
    moe_gate_kernel<<<grid, 256, 0, stream>>>(x, W, nw, noise,
                                              probs, idx_out, val_out, D);
}

// Round 5
// 235.492 us; speedup vs baseline: 3.1411x; 1.5118x over previous
//
#include <hip/hip_runtime.h>
#include <math.h>

// TopKMoEGate via split-bf16 MFMA:
//   x = xh + xl, W = wh + wl (bf16 hi/lo); logits = xh*wh + xh*wl + xl*wh
//   (fp32-accurate to ~5e-6; wave-parallel fp64 tie-guard on top-3 candidates
//    protects top-k index exactness — eps=1e-3 >> 5e-6 approx error).
// Block: 32 tokens x 64 experts, BK=64, double-buffered LDS, 1 barrier/iter.
// Wave w: token-half (w&1), expert-half (w>>1); 16x16x32 bf16 MFMA.

typedef __attribute__((ext_vector_type(8))) __bf16 bf16x8;
typedef __attribute__((ext_vector_type(8))) unsigned short u16x8;
typedef __attribute__((ext_vector_type(4))) float f32x4;

constexpr int EXPN = 64;   // experts
constexpr int BM   = 32;   // tokens per block
constexpr int BK   = 64;   // k chunk
constexpr int LDK  = BK + 8;  // 72 bf16 = 144 B row stride (16B-aligned)

__device__ __forceinline__ void split2(float f, unsigned short& h, unsigned short& l) {
    const unsigned b = __float_as_uint(f);
    h = (unsigned short)(b >> 16);                       // bf16 hi (truncate)
    const float fh = __uint_as_float(b & 0xffff0000u);
    l = (unsigned short)(__float_as_uint(f - fh) >> 16); // bf16 lo
}

__global__ __launch_bounds__(256)
void moe_gate_kernel(const float* __restrict__ x,      // [M, D]
                     const float* __restrict__ W,      // [E, D]
                     const float* __restrict__ nw,     // [E]
                     const float* __restrict__ noise,  // [M, E]
                     float* __restrict__ probs,        // [M, E]
                     float* __restrict__ idx_out,      // [M, 2] float-encoded
                     float* __restrict__ val_out,      // [M, 2]
                     int D)
{
    __shared__ unsigned short xh[2][BM][LDK], xl[2][BM][LDK];     // 18.4 KB
    __shared__ unsigned short wh[2][EXPN][LDK], wl[2][EXPN][LDK]; // 36.9 KB
    __shared__ float ls[BM][EXPN + 1];                            // 8.3 KB

    const int tid  = threadIdx.x;
    const int lane = tid & 63;
    const int wv   = tid >> 6;
    const int hh   = wv & 1;        // token half (16 tokens)
    const int qq   = wv >> 1;       // expert half (32 experts)
    const int m0   = blockIdx.x * BM;

    // staging assignment
    const int xrow = tid >> 3;          // 0..31 token
    const int xcol = (tid & 7) * 8;     // k offset (8 floats / thread)
    const int wrow = tid >> 2;          // 0..63 expert
    const int wcol = (tid & 3) * 16;    // k offset (16 floats / thread)

    const float* xbase = x + (size_t)(m0 + xrow) * D + xcol;
    const float* wbase = W + (size_t)wrow * D + wcol;

    f32x4 acc0 = {0.f, 0.f, 0.f, 0.f};
    f32x4 acc1 = {0.f, 0.f, 0.f, 0.f};

    float4 xr0, xr1, wr0, wr1, wr2, wr3;
    xr0 = *(const float4*)(xbase);
    xr1 = *(const float4*)(xbase + 4);
    wr0 = *(const float4*)(wbase);
    wr1 = *(const float4*)(wbase + 4);
    wr2 = *(const float4*)(wbase + 8);
    wr3 = *(const float4*)(wbase + 12);

    const int nchunk = D / BK;          // 32
    const int fr = lane & 15;           // m (tokens) / n (experts) in frag
    const int kq = (lane >> 4) * 8;     // k sub-offset in frag

    for (int c = 0; c < nchunk; ++c) {
        const int buf = c & 1;

        // ---- convert + stage into LDS ----
        {
            const float xv[8] = {xr0.x, xr0.y, xr0.z, xr0.w,
                                 xr1.x, xr1.y, xr1.z, xr1.w};
            u16x8 hv, lv;
#pragma unroll
            for (int i = 0; i < 8; ++i) {
                unsigned short a, b; split2(xv[i], a, b);
                hv[i] = a; lv[i] = b;
            }
            *(u16x8*)&xh[buf][xrow][xcol] = hv;
            *(u16x8*)&xl[buf][xrow][xcol] = lv;

            const float wvv[16] = {wr0.x, wr0.y, wr0.z, wr0.w,
                                   wr1.x, wr1.y, wr1.z, wr1.w,
                                   wr2.x, wr2.y, wr2.z, wr2.w,
                                   wr3.x, wr3.y, wr3.z, wr3.w};
            u16x8 h0, l0, h1, l1;
#pragma unroll
            for (int i = 0; i < 8; ++i) {
                unsigned short a, b; split2(wvv[i], a, b);
                h0[i] = a; l0[i] = b;
                split2(wvv[i + 8], a, b);
                h1[i] = a; l1[i] = b;
            }
            *(u16x8*)&wh[buf][wrow][wcol]     = h0;
            *(u16x8*)&wl[buf][wrow][wcol]     = l0;
            *(u16x8*)&wh[buf][wrow][wcol + 8] = h1;
            *(u16x8*)&wl[buf][wrow][wcol + 8] = l1;
        }
        __syncthreads();

        // ---- prefetch next chunk (lands during MFMA phase) ----
        if (c + 1 < nchunk) {
            const float* xp = xbase + (c + 1) * BK;
            xr0 = *(const float4*)(xp);
            xr1 = *(const float4*)(xp + 4);
            const float* wp = wbase + (c + 1) * BK;
            wr0 = *(const float4*)(wp);
            wr1 = *(const float4*)(wp + 4);
            wr2 = *(const float4*)(wp + 8);
            wr3 = *(const float4*)(wp + 12);
        }

        // ---- MFMA on current chunk ----
#pragma unroll
        for (int ks = 0; ks < BK; ks += 32) {
            const bf16x8 ah  = *(const bf16x8*)&xh[buf][hh * 16 + fr][ks + kq];
            const bf16x8 al  = *(const bf16x8*)&xl[buf][hh * 16 + fr][ks + kq];
            const bf16x8 b0h = *(const bf16x8*)&wh[buf][qq * 32 + fr][ks + kq];
            const bf16x8 b0l = *(const bf16x8*)&wl[buf][qq * 32 + fr][ks + kq];
            const bf16x8 b1h = *(const bf16x8*)&wh[buf][qq * 32 + 16 + fr][ks + kq];
            const bf16x8 b1l = *(const bf16x8*)&wl[buf][qq * 32 + 16 + fr][ks + kq];
            acc0 = __builtin_amdgcn_mfma_f32_16x16x32_bf16(ah, b0h, acc0, 0, 0, 0);
            acc0 = __builtin_amdgcn_mfma_f32_16x16x32_bf16(ah, b0l, acc0, 0, 0, 0);
            acc0 = __builtin_amdgcn_mfma_f32_16x16x32_bf16(al, b0h, acc0, 0, 0, 0);
            acc1 = __builtin_amdgcn_mfma_f32_16x16x32_bf16(ah, b1h, acc1, 0, 0, 0);
            acc1 = __builtin_amdgcn_mfma_f32_16x16x32_bf16(ah, b1l, acc1, 0, 0, 0);
            acc1 = __builtin_amdgcn_mfma_f32_16x16x32_bf16(al, b1h, acc1, 0, 0, 0);
        }
    }

    // ---- C/D layout: col = lane&15, row = (lane>>4)*4 + reg ----
    const int trow = hh * 16 + (lane >> 4) * 4;
#pragma unroll
    for (int r = 0; r < 4; ++r) {
        ls[trow + r][qq * 32 + fr]      = acc0[r];
        ls[trow + r][qq * 32 + 16 + fr] = acc1[r];
    }
    __syncthreads();

    // ---- epilogue: per-token noisy top-2 + sparse softmax (lane = expert) ----
    const float nwv = nw[lane];

#pragma unroll 1
    for (int t = 0; t < 8; ++t) {
        const int tl = wv * 8 + t;       // local token
        const int g  = m0 + tl;          // global token
        const float logit = fmaf(noise[(size_t)g * EXPN + lane], nwv, ls[tl][lane]);

        float v0; int i0;
        {
            float v = logit; int ix = lane;
#pragma unroll
            for (int off = 32; off; off >>= 1) {
                const float vo = __shfl_xor(v, off);
                const int   io = __shfl_xor(ix, off);
                if (vo > v || (vo == v && io < ix)) { v = vo; ix = io; }
            }
            v0 = v; i0 = ix;
        }
        float v1; int i1;
        {
            float v = (lane == i0) ? -INFINITY : logit; int ix = lane;
#pragma unroll
            for (int off = 32; off; off >>= 1) {
                const float vo = __shfl_xor(v, off);
                const int   io = __shfl_xor(ix, off);
                if (vo > v || (vo == v && io < ix)) { v = vo; ix = io; }
            }
            v1 = v; i1 = ix;
        }
        float v2; int i2;
        {
            float v = (lane == i0 || lane == i1) ? -INFINITY : logit; int ix = lane;
#pragma unroll
            for (int off = 32; off; off >>= 1) {
                const float vo = __shfl_xor(v, off);
                const int   io = __shfl_xor(ix, off);
                if (vo > v || (vo == v && io < ix)) { v = vo; ix = io; }
            }
            v2 = v; i2 = ix;
        }

        // near-tie guard: wave-parallel fp64 recompute of the 3 candidate
        // logits (lanes stride K by 64 -> coalesced; butterfly fp64 sum).
        const float eps = 1e-3f;
        if ((v0 - v1) < eps || (v1 - v2) < eps) {
            const float* xr  = x + (size_t)g * D;
            const float* w0r = W + (size_t)i0 * D;
            const float* w1r = W + (size_t)i1 * D;
            const float* w2r = W + (size_t)i2 * D;
            double s0 = 0.0, s1 = 0.0, s2 = 0.0;
            for (int d = lane; d < D; d += 64) {
                const double xv = (double)xr[d];
                s0 += xv * (double)w0r[d];
                s1 += xv * (double)w1r[d];
                s2 += xv * (double)w2r[d];
            }
#pragma unroll
            for (int off = 32; off; off >>= 1) {
                s0 += __shfl_xor(s0, off);
                s1 += __shfl_xor(s1, off);
                s2 += __shfl_xor(s2, off);
            }
            double d0 = s0 + (double)noise[(size_t)g * EXPN + i0] * (double)nw[i0];
            double d1 = s1 + (double)noise[(size_t)g * EXPN + i1] * (double)nw[i1];
            double d2 = s2 + (double)noise[(size_t)g * EXPN + i2] * (double)nw[i2];
            // sort 3 (value desc, index asc on ties)
            #define CSWAP(va, ia, vb, ib)                                   \
                if ((vb > va) || (vb == va && ib < ia)) {                   \
                    double tv = va; va = vb; vb = tv;                       \
                    int ti = ia; ia = ib; ib = ti; }
            CSWAP(d0, i0, d1, i1)
            CSWAP(d1, i1, d2, i2)
            CSWAP(d0, i0, d1, i1)
            #undef CSWAP
            v0 = (float)d0; v1 = (float)d1;
        }

        const float e1  = expf(v1 - v0);
        const float inv = 1.0f / (1.0f + e1);

        float p = 0.f;
        if (lane == i0)      p = inv;
        else if (lane == i1) p = e1 * inv;
        probs[(size_t)g * EXPN + lane] = p;

        if (lane == 0) {
            idx_out[(size_t)g * 2 + 0] = (float)i0;
            idx_out[(size_t)g * 2 + 1] = (float)i1;
            val_out[(size_t)g * 2 + 0] = v0;
            val_out[(size_t)g * 2 + 1] = v1;
        }
    }
}

extern "C" void kernel_launch(void* const* d_in, const int* in_sizes, int n_in,
                              void* d_out, int out_size, void* d_ws, size_t ws_size,
                              hipStream_t stream) {
    const float* x     = (const float*)d_in[0];  // [B,S,D]
    const float* W     = (const float*)d_in[1];  // [E,D]
    const float* nw    = (const float*)d_in[2];  // [E]
    const float* noise = (const float*)d_in[3];  // [B,S,E]

    const int M = in_sizes[3] / EXPN;            // 16384 tokens
    const int D = in_sizes[0] / M;               // 2048

    float* probs   = (float*)d_out;              // [M, E]
    float* idx_out = probs + (size_t)M * EXPN;   // [M, 2]
    float* val_out = idx_out + (size_t)M * 2;    // [M, 2]

    const int grid = M / BM;                     // 512 blocks
    moe_gate_kernel<<<grid, 256, 0, stream>>>(x, W, nw, noise,
                                              probs, idx_out, val_out, D);
}